// Round 8
// baseline (71.718 us; speedup 1.0000x reference)
//
#include <hip/hip_runtime.h>
#include <hip/hip_bf16.h>

#define IN_F 256
#define OUT_F 128
#define GEMM_THREADS 512      // 8 waves/block, each wave an independent 16x32 worker
#define GEMM_BLOCKS 512       // 4096 waves -> 12500 wave-tasks, ~3 each

typedef __bf16 bf16x8 __attribute__((ext_vector_type(8)));
typedef float  f32x4  __attribute__((ext_vector_type(4)));
typedef int    i32x4  __attribute__((ext_vector_type(4)));

// -------- Kernel 0: Wt[n][k] = bf16(W[k][n])  (128x256 bf16, 64 KB) --------
__global__ __launch_bounds__(128)
void wprep_kernel(const float* __restrict__ W, __bf16* __restrict__ Wt)
{
    const int k = blockIdx.x;      // 0..255
    const int nn = threadIdx.x;    // 0..127
    Wt[nn * IN_F + k] = (__bf16)W[k * OUT_F + nn];
}

// -------- Kernel 1: H = bf16(X @ W) via MFMA, barrier-free --------
// Each wave: one 16-row x 32-col output tile per task, A-frags direct from
// global (no LDS, no __syncthreads). Col-group is constant per wave.
__global__ __launch_bounds__(GEMM_THREADS, 3)
void gemm_xw_kernel(const float* __restrict__ X, const __bf16* __restrict__ Wt,
                    __bf16* __restrict__ H, int n, int nstripes)
{
    const int lane  = threadIdx.x & 63;
    const int wid   = threadIdx.x >> 6;                       // 0..7
    const int gwave = blockIdx.x * (GEMM_THREADS / 64) + wid; // 0..4095
    const int g     = gwave & 3;                              // col group 0..3 (constant)
    const int s0    = gwave >> 2;                             // starting stripe
    const int sstep = (GEMM_BLOCKS * (GEMM_THREADS / 64)) >> 2; // 1024

    // ---- B fragments once per wave (Wt is L2-resident) ----
    // frag layout: n = lane&15, k = (lane>>4)*8 + j
    bf16x8 bfrag[8][2];
    {
        const int nbase = g * 32 + (lane & 15);
        const int kbase = (lane >> 4) * 8;
        #pragma unroll
        for (int kk = 0; kk < 8; ++kk) {
            #pragma unroll
            for (int nf = 0; nf < 2; ++nf) {
                const __bf16* p = Wt + (size_t)(nbase + nf * 16) * IN_F + kk * 32 + kbase;
                bfrag[kk][nf] = *(const bf16x8*)p;
            }
        }
    }

    const int arow_off = lane & 15;        // A row within stripe
    const int akoff    = (lane >> 4) * 8;  // A k offset within 32-wide k-slab

    for (int s = s0; s < nstripes; s += sstep) {
        const int r0 = s * 16;
        // clamp (n is a multiple of 16 in practice; clamp keeps safety w/o branch)
        const int arow = min(r0 + arow_off, n - 1);
        const float* pX = X + (size_t)arow * IN_F + akoff;

        f32x4 acc0 = (f32x4)0.f, acc1 = (f32x4)0.f;
        #pragma unroll
        for (int kk = 0; kk < 8; ++kk) {
            const float4 x0 = *(const float4*)(pX + kk * 32);
            const float4 x1 = *(const float4*)(pX + kk * 32 + 4);
            bf16x8 a;
            a[0]=(__bf16)x0.x; a[1]=(__bf16)x0.y; a[2]=(__bf16)x0.z; a[3]=(__bf16)x0.w;
            a[4]=(__bf16)x1.x; a[5]=(__bf16)x1.y; a[6]=(__bf16)x1.z; a[7]=(__bf16)x1.w;
            acc0 = __builtin_amdgcn_mfma_f32_16x16x32_bf16(a, bfrag[kk][0], acc0, 0, 0, 0);
            acc1 = __builtin_amdgcn_mfma_f32_16x16x32_bf16(a, bfrag[kk][1], acc1, 0, 0, 0);
        }

        // store (C/D layout: col=lane&15, row=(lane>>4)*4+j)
        const int crow0 = r0 + (lane >> 4) * 4;
        const int ccol0 = g * 32 + (lane & 15);
        #pragma unroll
        for (int j = 0; j < 4; ++j) {
            const int row = crow0 + j;
            if (row < n) {
                H[(size_t)row * OUT_F + ccol0]      = (__bf16)acc0[j];
                H[(size_t)row * OUT_F + ccol0 + 16] = (__bf16)acc1[j];
            }
        }
    }
}

// -------- Kernel 2: out = relu(A @ H + bias)  (CSR, H bf16, acc f32) --------
__global__ __launch_bounds__(256, 4)
void spmm_bias_relu_kernel(const int* __restrict__ row_ptr,
                           const int* __restrict__ col_idx,
                           const float* __restrict__ val,
                           const __bf16* __restrict__ H,
                           const float* __restrict__ bias,
                           float* __restrict__ out, int n)
{
    const int row = blockIdx.x * 16 + (threadIdx.x >> 4);
    const int c8  = (threadIdx.x & 15) * 8;
    if (row >= n) return;

    const int s = row_ptr[row];
    const int e = row_ptr[row + 1];

    // bias is tiny and cached; load early (independent of gathers)
    const f32x4 b0 = *(const f32x4*)(bias + c8);
    const f32x4 b1 = *(const f32x4*)(bias + c8 + 4);

    float acc[8];
    #pragma unroll
    for (int j = 0; j < 8; ++j) acc[j] = 0.f;

    if (e - s == 16 && (s & 3) == 0) {
        // fast path: 16 edges; nontemporal metadata (read-once), cached H gathers
        i32x4 ci[4];
        f32x4 vi[4];
        #pragma unroll
        for (int i = 0; i < 4; ++i) {
            ci[i] = __builtin_nontemporal_load((const i32x4*)(col_idx + s) + i);
            vi[i] = __builtin_nontemporal_load((const f32x4*)(val + s) + i);
        }
        bf16x8 hv[16];
        #pragma unroll
        for (int i = 0; i < 16; ++i)
            hv[i] = *(const bf16x8*)(H + (size_t)ci[i >> 2][i & 3] * OUT_F + c8);
        #pragma unroll
        for (int i = 0; i < 16; ++i) {
            const float v = vi[i >> 2][i & 3];
            #pragma unroll
            for (int j = 0; j < 8; ++j)
                acc[j] = fmaf(v, (float)hv[i][j], acc[j]);
        }
    } else {
        for (int ee = s; ee < e; ++ee) {
            const int   col = col_idx[ee];
            const float v   = val[ee];
            const bf16x8 hv = *(const bf16x8*)(H + (size_t)col * OUT_F + c8);
            #pragma unroll
            for (int j = 0; j < 8; ++j)
                acc[j] = fmaf(v, (float)hv[j], acc[j]);
        }
    }

    f32x4 o0 = { fmaxf(acc[0] + b0[0], 0.f), fmaxf(acc[1] + b0[1], 0.f),
                 fmaxf(acc[2] + b0[2], 0.f), fmaxf(acc[3] + b0[3], 0.f) };
    f32x4 o1 = { fmaxf(acc[4] + b1[0], 0.f), fmaxf(acc[5] + b1[1], 0.f),
                 fmaxf(acc[6] + b1[2], 0.f), fmaxf(acc[7] + b1[3], 0.f) };
    __builtin_nontemporal_store(o0, (f32x4*)(out + (size_t)row * OUT_F + c8));
    __builtin_nontemporal_store(o1, (f32x4*)(out + (size_t)row * OUT_F + c8 + 4));
}

extern "C" void kernel_launch(void* const* d_in, const int* in_sizes, int n_in,
                              void* d_out, int out_size, void* d_ws, size_t ws_size,
                              hipStream_t stream)
{
    const int*   row_ptr = (const int*)  d_in[1];
    const int*   col_idx = (const int*)  d_in[2];
    const float* edgeval = (const float*)d_in[3];
    const float* in_feat = (const float*)d_in[11];
    const float* W       = (const float*)d_in[12];
    const float* bias    = (const float*)d_in[13];

    const int n = in_sizes[11] / IN_F;   // 50000 nodes

    __bf16* H  = (__bf16*)d_ws;                                  // [n][128] bf16
    __bf16* Wt = (__bf16*)((char*)d_ws + (size_t)n * OUT_F * 2); // [128][256] bf16

    wprep_kernel<<<IN_F, OUT_F, 0, stream>>>(W, Wt);

    const int nstripes = (n + 15) / 16;   // 3125
    gemm_xw_kernel<<<GEMM_BLOCKS, GEMM_THREADS, 0, stream>>>(in_feat, Wt, H, n, nstripes);

    const int spmm_blocks = (n + 15) / 16;
    spmm_bias_relu_kernel<<<spmm_blocks, 256, 0, stream>>>(
        row_ptr, col_idx, edgeval, H, bias, (float*)d_out, n);
}

// Round 9
// 50.934 us; speedup vs baseline: 1.4080x; 1.4080x over previous
//
#include <hip/hip_runtime.h>
#include <hip/hip_bf16.h>

#define IN_F 256
#define OUT_F 128
#define BM 32                 // GEMM rows per tile
#define GEMM_THREADS 512      // 8 waves: 2 (M) x 4 (N)
#define GEMM_BLOCKS 512       // 2 blocks/CU exactly; grid-stride over tiles

typedef __bf16 bf16x8 __attribute__((ext_vector_type(8)));
typedef float  f32x4  __attribute__((ext_vector_type(4)));
typedef int    i32x4  __attribute__((ext_vector_type(4)));

// -------- Kernel 1: H = bf16(X @ W) via MFMA, persistent blocks --------
// B-fragments built in-register from raw f32 W (no wprep kernel, no Wt scratch).
__global__ __launch_bounds__(GEMM_THREADS)
void gemm_xw_kernel(const float* __restrict__ X, const float* __restrict__ W,
                    __bf16* __restrict__ H, int n, int ntiles)
{
    __shared__ __bf16 xs[2][BM * IN_F];   // 2 x 16 KB, XOR-swizzled

    const int tid  = threadIdx.x;
    const int lane = tid & 63;
    const int wid  = tid >> 6;         // 0..7
    const int wm   = wid >> 2;         // 0..1 (16-row band)
    const int wn   = wid & 3;          // 0..3 (32-col band)

    // per-thread staging coords: chunk0 -> rows 0..15, chunk1 -> rows 16..31
    const int srow = tid >> 5;           // 0..15
    const int sk   = (tid & 31) * 8;     // 0..248

    // ---- prologue: stage first tile into buf 0 (issue before W gather) ----
    int tile = blockIdx.x;
    if (tile < ntiles) {
        const int r0 = tile * BM;
        float4 a0 = make_float4(0,0,0,0), a1 = a0, b0 = a0, b1 = a0;
        const int gr0 = r0 + srow, gr1 = r0 + srow + 16;
        if (gr0 < n) {
            a0 = *(const float4*)(X + (size_t)gr0 * IN_F + sk);
            a1 = *(const float4*)(X + (size_t)gr0 * IN_F + sk + 4);
        }
        if (gr1 < n) {
            b0 = *(const float4*)(X + (size_t)gr1 * IN_F + sk);
            b1 = *(const float4*)(X + (size_t)gr1 * IN_F + sk + 4);
        }
        bf16x8 v0, v1;
        v0[0]=(__bf16)a0.x; v0[1]=(__bf16)a0.y; v0[2]=(__bf16)a0.z; v0[3]=(__bf16)a0.w;
        v0[4]=(__bf16)a1.x; v0[5]=(__bf16)a1.y; v0[6]=(__bf16)a1.z; v0[7]=(__bf16)a1.w;
        v1[0]=(__bf16)b0.x; v1[1]=(__bf16)b0.y; v1[2]=(__bf16)b0.z; v1[3]=(__bf16)b0.w;
        v1[4]=(__bf16)b1.x; v1[5]=(__bf16)b1.y; v1[6]=(__bf16)b1.z; v1[7]=(__bf16)b1.w;
        *(bf16x8*)&xs[0][(srow * IN_F + sk) ^ ((srow & 7) << 3)] = v0;
        *(bf16x8*)&xs[0][((srow + 16) * IN_F + sk) ^ (((srow + 16) & 7) << 3)] = v1;
    }

    // ---- build B fragments from raw W (L2-resident; once per block) ----
    // frag layout: n = lane&15, k = (lane>>4)*8 + j
    bf16x8 bfrag[8][2];
    {
        const int nbase = wn * 32 + (lane & 15);
        const int kbase = (lane >> 4) * 8;
        #pragma unroll
        for (int kk = 0; kk < 8; ++kk) {
            #pragma unroll
            for (int nf = 0; nf < 2; ++nf) {
                #pragma unroll
                for (int j = 0; j < 8; ++j)
                    bfrag[kk][nf][j] =
                        (__bf16)W[(size_t)(kk * 32 + kbase + j) * OUT_F + nbase + nf * 16];
            }
        }
    }
    __syncthreads();

    int cur = 0;
    for (; tile < ntiles; tile += gridDim.x) {
        const int nxt = tile + (int)gridDim.x;
        const bool has_next = nxt < ntiles;

        // ---- issue next tile's global loads early (hide under MFMA) ----
        float4 a0 = make_float4(0,0,0,0), a1 = a0, b0 = a0, b1 = a0;
        if (has_next) {
            const int r0 = nxt * BM;
            const int gr0 = r0 + srow, gr1 = r0 + srow + 16;
            if (gr0 < n) {
                a0 = *(const float4*)(X + (size_t)gr0 * IN_F + sk);
                a1 = *(const float4*)(X + (size_t)gr0 * IN_F + sk + 4);
            }
            if (gr1 < n) {
                b0 = *(const float4*)(X + (size_t)gr1 * IN_F + sk);
                b1 = *(const float4*)(X + (size_t)gr1 * IN_F + sk + 4);
            }
        }

        // ---- MFMA on current buffer ----
        f32x4 acc0 = (f32x4)0.f, acc1 = (f32x4)0.f;
        {
            const int arow  = wm * 16 + (lane & 15);
            const int akoff = (lane >> 4) * 8;
            #pragma unroll
            for (int kk = 0; kk < 8; ++kk) {
                const int sidx = (arow * IN_F + kk * 32 + akoff) ^ ((arow & 7) << 3);
                const bf16x8 a = *(const bf16x8*)&xs[cur][sidx];
                acc0 = __builtin_amdgcn_mfma_f32_16x16x32_bf16(a, bfrag[kk][0], acc0, 0, 0, 0);
                acc1 = __builtin_amdgcn_mfma_f32_16x16x32_bf16(a, bfrag[kk][1], acc1, 0, 0, 0);
            }
        }

        // ---- store H tile (C/D layout: col=lane&15, row=(lane>>4)*4+j) ----
        {
            const int crow0 = tile * BM + wm * 16 + (lane >> 4) * 4;
            const int ccol0 = wn * 32 + (lane & 15);
            #pragma unroll
            for (int j = 0; j < 4; ++j) {
                const int row = crow0 + j;
                if (row < n) {
                    H[(size_t)row * OUT_F + ccol0]      = (__bf16)acc0[j];
                    H[(size_t)row * OUT_F + ccol0 + 16] = (__bf16)acc1[j];
                }
            }
        }

        // ---- convert + write next tile into the other buffer ----
        if (has_next) {
            bf16x8 v0, v1;
            v0[0]=(__bf16)a0.x; v0[1]=(__bf16)a0.y; v0[2]=(__bf16)a0.z; v0[3]=(__bf16)a0.w;
            v0[4]=(__bf16)a1.x; v0[5]=(__bf16)a1.y; v0[6]=(__bf16)a1.z; v0[7]=(__bf16)a1.w;
            v1[0]=(__bf16)b0.x; v1[1]=(__bf16)b0.y; v1[2]=(__bf16)b0.z; v1[3]=(__bf16)b0.w;
            v1[4]=(__bf16)b1.x; v1[5]=(__bf16)b1.y; v1[6]=(__bf16)b1.z; v1[7]=(__bf16)b1.w;
            const int nb = cur ^ 1;
            *(bf16x8*)&xs[nb][(srow * IN_F + sk) ^ ((srow & 7) << 3)] = v0;
            *(bf16x8*)&xs[nb][((srow + 16) * IN_F + sk) ^ (((srow + 16) & 7) << 3)] = v1;
        }
        __syncthreads();
        cur ^= 1;
    }
}

// -------- Kernel 2: out = relu(A @ H + bias)  (CSR, H bf16, acc f32) --------
__global__ __launch_bounds__(256, 4)
void spmm_bias_relu_kernel(const int* __restrict__ row_ptr,
                           const int* __restrict__ col_idx,
                           const float* __restrict__ val,
                           const __bf16* __restrict__ H,
                           const float* __restrict__ bias,
                           float* __restrict__ out, int n)
{
    const int row = blockIdx.x * 16 + (threadIdx.x >> 4);
    const int c8  = (threadIdx.x & 15) * 8;
    if (row >= n) return;

    const int s = row_ptr[row];
    const int e = row_ptr[row + 1];

    // bias is tiny and cached; load early (independent of gathers)
    const f32x4 b0 = *(const f32x4*)(bias + c8);
    const f32x4 b1 = *(const f32x4*)(bias + c8 + 4);

    float acc[8];
    #pragma unroll
    for (int j = 0; j < 8; ++j) acc[j] = 0.f;

    if (e - s == 16 && (s & 3) == 0) {
        // fast path: 16 edges; nontemporal metadata (read-once), cached H gathers
        i32x4 ci[4];
        f32x4 vi[4];
        #pragma unroll
        for (int i = 0; i < 4; ++i) {
            ci[i] = __builtin_nontemporal_load((const i32x4*)(col_idx + s) + i);
            vi[i] = __builtin_nontemporal_load((const f32x4*)(val + s) + i);
        }
        bf16x8 hv[16];
        #pragma unroll
        for (int i = 0; i < 16; ++i)
            hv[i] = *(const bf16x8*)(H + (size_t)ci[i >> 2][i & 3] * OUT_F + c8);
        #pragma unroll
        for (int i = 0; i < 16; ++i) {
            const float v = vi[i >> 2][i & 3];
            #pragma unroll
            for (int j = 0; j < 8; ++j)
                acc[j] = fmaf(v, (float)hv[i][j], acc[j]);
        }
    } else {
        for (int ee = s; ee < e; ++ee) {
            const int   col = col_idx[ee];
            const float v   = val[ee];
            const bf16x8 hv = *(const bf16x8*)(H + (size_t)col * OUT_F + c8);
            #pragma unroll
            for (int j = 0; j < 8; ++j)
                acc[j] = fmaf(v, (float)hv[j], acc[j]);
        }
    }

    f32x4 o0 = { fmaxf(acc[0] + b0[0], 0.f), fmaxf(acc[1] + b0[1], 0.f),
                 fmaxf(acc[2] + b0[2], 0.f), fmaxf(acc[3] + b0[3], 0.f) };
    f32x4 o1 = { fmaxf(acc[4] + b1[0], 0.f), fmaxf(acc[5] + b1[1], 0.f),
                 fmaxf(acc[6] + b1[2], 0.f), fmaxf(acc[7] + b1[3], 0.f) };
    __builtin_nontemporal_store(o0, (f32x4*)(out + (size_t)row * OUT_F + c8));
    __builtin_nontemporal_store(o1, (f32x4*)(out + (size_t)row * OUT_F + c8 + 4));
}

extern "C" void kernel_launch(void* const* d_in, const int* in_sizes, int n_in,
                              void* d_out, int out_size, void* d_ws, size_t ws_size,
                              hipStream_t stream)
{
    const int*   row_ptr = (const int*)  d_in[1];
    const int*   col_idx = (const int*)  d_in[2];
    const float* edgeval = (const float*)d_in[3];
    const float* in_feat = (const float*)d_in[11];
    const float* W       = (const float*)d_in[12];
    const float* bias    = (const float*)d_in[13];

    const int n = in_sizes[11] / IN_F;   // 50000 nodes

    __bf16* H = (__bf16*)d_ws;           // [n][128] bf16 scratch

    const int ntiles = (n + BM - 1) / BM;                        // 1563
    const int gemm_blocks = ntiles < GEMM_BLOCKS ? ntiles : GEMM_BLOCKS;
    gemm_xw_kernel<<<gemm_blocks, GEMM_THREADS, 0, stream>>>(in_feat, W, H, n, ntiles);

    const int spmm_blocks = (n + 15) / 16;
    spmm_bias_relu_kernel<<<spmm_blocks, 256, 0, stream>>>(
        row_ptr, col_idx, edgeval, H, bias, (float*)d_out, n);
}